// Round 1
// baseline (250.979 us; speedup 1.0000x reference)
//
#include <hip/hip_runtime.h>

typedef _Float16 f16;
typedef _Float16 f16x8 __attribute__((ext_vector_type(8)));
typedef _Float16 f16x4 __attribute__((ext_vector_type(4)));
typedef float f32x4 __attribute__((ext_vector_type(4)));

#define LOG2E 1.44269504088896f

// ---------------- W convert fp32 -> f16 ----------------
__global__ void k_wcvt(const float* __restrict__ w, f16* __restrict__ wh) {
    int i = (blockIdx.x * 256 + threadIdx.x) * 4;
    float4 v = *(const float4*)(w + i);
    f16x4 o = { (f16)v.x, (f16)v.y, (f16)v.z, (f16)v.w };
    *(f16x4*)(wh + i) = o;
}

// ------- depthwise 3x3 conv + transpose [B,C,N]->[B,N,C] + f16 cast -------
// grid: (ht=16, ct=6, b=16), 256 threads. Block covers 64 channels x 2 image rows.
__launch_bounds__(256)
__global__ void k_prep(const float* __restrict__ x, const float* __restrict__ wdw,
                       const float* __restrict__ bdw,
                       f16* __restrict__ xt, f16* __restrict__ rbt) {
    int ht = blockIdx.x, ct = blockIdx.y, b = blockIdx.z;
    __shared__ float xs[64 * 129];   // 64 channels x 128 n (4 image rows), pad 129
    int t = threadIdx.x;
    int h0 = ht * 2;
#pragma unroll
    for (int i = 0; i < 8; ++i) {
        int idx = t + i * 256;            // 2048 float4 granules
        int cl = idx >> 5, col4 = idx & 31;
        int hh = h0 - 1 + (col4 >> 3);    // image row: h0-1 .. h0+2
        int wq = (col4 & 7) * 4;
        float4 v = make_float4(0.f, 0.f, 0.f, 0.f);
        if (hh >= 0 && hh < 32)
            v = *(const float4*)(x + (size_t)(b * 384 + ct * 64 + cl) * 1024 + hh * 32 + wq);
        int base = cl * 129 + col4 * 4;
        xs[base] = v.x; xs[base + 1] = v.y; xs[base + 2] = v.z; xs[base + 3] = v.w;
    }
    __syncthreads();
    int cl = t & 63;
    int c = ct * 64 + cl;
    float wd[9];
#pragma unroll
    for (int k = 0; k < 9; ++k) wd[k] = wdw[c * 9 + k];
    float bd = bdw[c];
    const float* row = &xs[cl * 129];
    int nb = (t >> 6) * 16;
#pragma unroll
    for (int i = 0; i < 16; ++i) {
        int nl = nb + i;
        int hh = nl >> 5, ww = nl & 31;
        int lx = hh + 1;                  // LDS row of center (h - (h0-1))
        float acc = bd;
#pragma unroll
        for (int dh = -1; dh <= 1; ++dh) {
#pragma unroll
            for (int dw = -1; dw <= 1; ++dw) {
                int w2 = ww + dw;
                if (w2 >= 0 && w2 <= 31)
                    acc += wd[(dh + 1) * 3 + (dw + 1)] * row[(lx + dh) * 32 + w2];
            }
        }
        float xc = row[lx * 32 + ww];
        size_t at = ((size_t)(b * 1024) + h0 * 32 + nl) * 384 + c;
        rbt[at] = (f16)acc;   // coalesced: lane = channel
        xt[at] = (f16)xc;
    }
}

// ---------------- QKV GEMM: [B,N,C] x [1152,C]^T -> q,k+rb [B,N,C], v -> vT [B,C,N]
// grid: (bm=8, bn=9, b=16), 256 threads (4 waves, 2x2), tile 128x128, BK=64.
__launch_bounds__(256, 2)
__global__ void k_gemm1(const f16* __restrict__ xt, const f16* __restrict__ wh,
                        const float* __restrict__ bias, const f16* __restrict__ rbt,
                        f16* __restrict__ qo, f16* __restrict__ krb, f16* __restrict__ vt) {
    int bm = blockIdx.x, bn = blockIdx.y, b = blockIdx.z;
    __shared__ f16 As[128 * 64];   // [n_local][c] 128B rows, XOR swizzled
    __shared__ f16 Bs[128 * 64];   // [o_local][c]
    int t = threadIdx.x;
    int lane = t & 63, wv = t >> 6;
    int wm = wv >> 1, wn = wv & 1;
    f32x4 acc[4][4] = {};
    const f16* xbase = xt + (size_t)(b * 1024 + bm * 128) * 384;
    const f16* wbase = wh + (size_t)(bn * 128) * 384;
    const bool vmode = (bn >= 6);
    for (int kc = 0; kc < 384; kc += 64) {
        __syncthreads();
#pragma unroll
        for (int i = 0; i < 4; ++i) {
            int idx = t + i * 256;
            int rowi = idx >> 3, x16 = idx & 7;
            int off = rowi * 128 + ((x16 * 16) ^ ((rowi & 7) << 4));
            uint4 da = *(const uint4*)(xbase + rowi * 384 + kc + x16 * 8);
            *(uint4*)((char*)As + off) = da;
            uint4 db = *(const uint4*)(wbase + rowi * 384 + kc + x16 * 8);
            *(uint4*)((char*)Bs + off) = db;
        }
        __syncthreads();
#pragma unroll
        for (int j = 0; j < 2; ++j) {
            f16x8 af[4], bf[4];
#pragma unroll
            for (int mr = 0; mr < 4; ++mr) {
                int rowi = wm * 64 + mr * 16 + (lane & 15);
                af[mr] = *(const f16x8*)((const char*)As + rowi * 128 +
                         ((j * 64 + (lane >> 4) * 16) ^ ((rowi & 7) << 4)));
            }
#pragma unroll
            for (int nr = 0; nr < 4; ++nr) {
                int rowi = wn * 64 + nr * 16 + (lane & 15);
                bf[nr] = *(const f16x8*)((const char*)Bs + rowi * 128 +
                         ((j * 64 + (lane >> 4) * 16) ^ ((rowi & 7) << 4)));
            }
            if (!vmode) {
#pragma unroll
                for (int mr = 0; mr < 4; ++mr)
#pragma unroll
                    for (int nr = 0; nr < 4; ++nr)
                        acc[mr][nr] = __builtin_amdgcn_mfma_f32_16x16x32_f16(af[mr], bf[nr], acc[mr][nr], 0, 0, 0);
            } else {
                // swapped operands: D rows = o, cols = n -> direct vT stores
#pragma unroll
                for (int mr = 0; mr < 4; ++mr)
#pragma unroll
                    for (int nr = 0; nr < 4; ++nr)
                        acc[mr][nr] = __builtin_amdgcn_mfma_f32_16x16x32_f16(bf[nr], af[mr], acc[mr][nr], 0, 0, 0);
            }
        }
    }
    int o0 = bn * 128;
    if (!vmode) {
#pragma unroll
        for (int nr = 0; nr < 4; ++nr) {
            int o = o0 + wn * 64 + nr * 16 + (lane & 15);
            float bs = bias[o];
#pragma unroll
            for (int mr = 0; mr < 4; ++mr) {
                int n_l = wm * 64 + mr * 16 + ((lane >> 4) << 2);
#pragma unroll
                for (int r = 0; r < 4; ++r) {
                    int n_sp = bm * 128 + n_l + r;
                    size_t at = (size_t)(b * 1024 + n_sp) * 384;
                    float vv = acc[mr][nr][r] + bs;
                    if (o < 384) qo[at + o] = (f16)vv;
                    else krb[at + (o - 384)] = (f16)(vv + (float)rbt[at + (o - 384)]);
                }
            }
        }
    } else {
#pragma unroll
        for (int nr = 0; nr < 4; ++nr) {
#pragma unroll
            for (int mr = 0; mr < 4; ++mr) {
                int n_sp = bm * 128 + wm * 64 + mr * 16 + (lane & 15);
                int o_l = wn * 64 + nr * 16 + ((lane >> 4) << 2);
#pragma unroll
                for (int r = 0; r < 4; ++r) {
                    float vv = acc[mr][nr][r] + bias[o0 + o_l + r];
                    vt[(size_t)(b * 384 + (o0 - 768) + o_l + r) * 1024 + n_sp] = (f16)vv;
                }
            }
        }
    }
}

// ---------------- flash attention ----------------
// grid: (qt=16, b=16), 256 threads (4 waves). Wave owns 16 q-rows; Q in regs.
__launch_bounds__(256, 1)
__global__ void k_flash(const f16* __restrict__ q, const f16* __restrict__ krb,
                        const f16* __restrict__ vt, float* __restrict__ out) {
    int qt = blockIdx.x, b = blockIdx.y;
    __shared__ char smem[33792];
    f16* kvs = (f16*)smem;             // 16 KB K/V stage (shared between phases)
    f16* ps  = (f16*)(smem + 16384);   // 8 KB P tile
    float* ot = (float*)smem;          // epilogue [128 c][66] reuse
    int t = threadIdx.x, lane = t & 63, wv = t >> 6;
    int n0 = qt * 64;
    f16x8 qf[12];
    {
        const f16* qb = q + (size_t)(b * 1024 + n0 + wv * 16 + (lane & 15)) * 384 + (lane >> 4) * 8;
#pragma unroll
        for (int ks = 0; ks < 12; ++ks) qf[ks] = *(const f16x8*)(qb + ks * 32);
    }
    f32x4 oa[24] = {};
    float m_run[4] = { -1e30f, -1e30f, -1e30f, -1e30f };
    float l_run[4] = { 0.f, 0.f, 0.f, 0.f };
    for (int kt = 0; kt < 16; ++kt) {
        f32x4 s[4] = {};
#pragma unroll
        for (int cc = 0; cc < 3; ++cc) {
            __syncthreads();
            const f16* kb = krb + (size_t)(b * 1024 + kt * 64) * 384 + cc * 128;
#pragma unroll
            for (int i = 0; i < 4; ++i) {
                int idx = t + i * 256;
                int rowi = idx >> 4, x16 = idx & 15;
                uint4 d = *(const uint4*)(kb + rowi * 384 + x16 * 8);
                *(uint4*)((char*)kvs + rowi * 256 + ((x16 * 16) ^ ((rowi & 7) << 4))) = d;
            }
            __syncthreads();
#pragma unroll
            for (int j = 0; j < 4; ++j) {
#pragma unroll
                for (int nr = 0; nr < 4; ++nr) {
                    int rowi = nr * 16 + (lane & 15);
                    f16x8 bf = *(const f16x8*)((const char*)kvs + rowi * 256 +
                               ((j * 64 + (lane >> 4) * 16) ^ ((rowi & 7) << 4)));
                    s[nr] = __builtin_amdgcn_mfma_f32_16x16x32_f16(qf[cc * 4 + j], bf, s[nr], 0, 0, 0);
                }
            }
        }
        // ---- online softmax (rows = wave's 16 q rows; per lane 4 rows) ----
        float p[4][4];
#pragma unroll
        for (int r = 0; r < 4; ++r) {
            float m = fmaxf(fmaxf(s[0][r], s[1][r]), fmaxf(s[2][r], s[3][r]));
#pragma unroll
            for (int d = 1; d < 16; d <<= 1) m = fmaxf(m, __shfl_xor(m, d));
            float mn = fmaxf(m_run[r], m);
            float sc = exp2f((m_run[r] - mn) * LOG2E);
            m_run[r] = mn;
            float sum = 0.f;
#pragma unroll
            for (int nr = 0; nr < 4; ++nr) {
                float pv = exp2f((s[nr][r] - mn) * LOG2E);
                p[nr][r] = pv;
                sum += pv;
            }
#pragma unroll
            for (int d = 1; d < 16; d <<= 1) sum += __shfl_xor(sum, d);
            l_run[r] = l_run[r] * sc + sum;
#pragma unroll
            for (int cf = 0; cf < 24; ++cf) oa[cf][r] *= sc;
        }
        // ---- write P (f16, swizzled) ----
#pragma unroll
        for (int nr = 0; nr < 4; ++nr)
#pragma unroll
            for (int r = 0; r < 4; ++r) {
                int prow = wv * 16 + ((lane >> 4) << 2) + r;
                int pcol = nr * 16 + (lane & 15);
                *(f16*)((char*)ps + prow * 128 + ((pcol * 2) ^ ((prow & 7) << 4))) = (f16)p[nr][r];
            }
        __syncthreads();
        // ---- PV ----
#pragma unroll
        for (int cc2 = 0; cc2 < 3; ++cc2) {
            const f16* vb = vt + (size_t)(b * 384 + cc2 * 128) * 1024 + kt * 64;
#pragma unroll
            for (int i = 0; i < 4; ++i) {
                int idx = t + i * 256;
                int rowi = idx >> 3, x16 = idx & 7;
                uint4 d = *(const uint4*)(vb + rowi * 1024 + x16 * 8);
                *(uint4*)((char*)kvs + rowi * 128 + ((x16 * 16) ^ ((rowi & 7) << 4))) = d;
            }
            __syncthreads();
#pragma unroll
            for (int j = 0; j < 2; ++j) {
                int prow = wv * 16 + (lane & 15);
                f16x8 pa = *(const f16x8*)((const char*)ps + prow * 128 +
                           ((j * 64 + (lane >> 4) * 16) ^ ((prow & 7) << 4)));
#pragma unroll
                for (int nr2 = 0; nr2 < 8; ++nr2) {
                    int rowi = nr2 * 16 + (lane & 15);
                    f16x8 bf = *(const f16x8*)((const char*)kvs + rowi * 128 +
                               ((j * 64 + (lane >> 4) * 16) ^ ((rowi & 7) << 4)));
                    oa[cc2 * 8 + nr2] = __builtin_amdgcn_mfma_f32_16x16x32_f16(pa, bf, oa[cc2 * 8 + nr2], 0, 0, 0);
                }
            }
            __syncthreads();
        }
    }
    // ---- epilogue: O/l, transpose via LDS, store out[b][c][n] coalesced ----
    float inv[4];
#pragma unroll
    for (int r = 0; r < 4; ++r) inv[r] = 1.0f / l_run[r];
#pragma unroll
    for (int cc2 = 0; cc2 < 3; ++cc2) {
        __syncthreads();
#pragma unroll
        for (int nr2 = 0; nr2 < 8; ++nr2) {
            int c_l = nr2 * 16 + (lane & 15);
            int qrow = wv * 16 + ((lane >> 4) << 2);
#pragma unroll
            for (int r = 0; r < 4; ++r)
                ot[c_l * 66 + qrow + r] = oa[cc2 * 8 + nr2][r] * inv[r];
        }
        __syncthreads();
        for (int rr = 0; rr < 32; ++rr) {
            int crow = wv * 32 + rr;
            out[(size_t)(b * 384 + cc2 * 128 + crow) * 1024 + n0 + lane] = ot[crow * 66 + lane];
        }
    }
}

extern "C" void kernel_launch(void* const* d_in, const int* in_sizes, int n_in,
                              void* d_out, int out_size, void* d_ws, size_t ws_size,
                              hipStream_t stream) {
    const float* x     = (const float*)d_in[0];
    const float* w_qkv = (const float*)d_in[1];
    const float* b_qkv = (const float*)d_in[2];
    const float* w_dw  = (const float*)d_in[3];
    const float* b_dw  = (const float*)d_in[4];
    float* out = (float*)d_out;
    char* ws = (char*)d_ws;
    const size_t SZ = (size_t)16 * 1024 * 384 * 2;  // 12.58 MB per f16 tensor
    f16* xt  = (f16*)(ws);
    f16* rbt = (f16*)(ws + SZ);
    f16* qo  = (f16*)(ws + 2 * SZ);
    f16* krb = (f16*)(ws + 3 * SZ);
    f16* vt  = (f16*)(ws + 4 * SZ);
    f16* wh  = (f16*)(ws + 5 * SZ);

    k_wcvt<<<432, 256, 0, stream>>>(w_qkv, wh);
    k_prep<<<dim3(16, 6, 16), 256, 0, stream>>>(x, w_dw, b_dw, xt, rbt);
    k_gemm1<<<dim3(8, 9, 16), 256, 0, stream>>>(xt, wh, b_qkv, rbt, qo, krb, vt);
    k_flash<<<dim3(16, 16), 256, 0, stream>>>(qo, krb, vt, out);
}

// Round 4
// 207.082 us; speedup vs baseline: 1.2120x; 1.2120x over previous
//
#include <hip/hip_runtime.h>

typedef _Float16 f16;
typedef _Float16 f16x8 __attribute__((ext_vector_type(8)));
typedef _Float16 f16x4 __attribute__((ext_vector_type(4)));
typedef _Float16 f16x2 __attribute__((ext_vector_type(2)));
typedef float f32x4 __attribute__((ext_vector_type(4)));

#define L2E 1.44269504088896f

typedef __attribute__((address_space(1))) void GV;
typedef __attribute__((address_space(3))) void LV;
__device__ __forceinline__ void gl2lds(const void* gp, void* lp) {
    __builtin_amdgcn_global_load_lds((GV*)gp, (LV*)lp, 16, 0, 0);
}

// ---------------- W convert fp32 -> f16 ----------------
__global__ void k_wcvt(const float* __restrict__ w, f16* __restrict__ wh) {
    int i = (blockIdx.x * 256 + threadIdx.x) * 4;
    float4 v = *(const float4*)(w + i);
    f16x4 o = { (f16)v.x, (f16)v.y, (f16)v.z, (f16)v.w };
    *(f16x4*)(wh + i) = o;
}

// ------- depthwise 3x3 conv + transpose [B,C,N]->[B,N,C] + f16 cast -------
__launch_bounds__(256)
__global__ void k_prep(const float* __restrict__ x, const float* __restrict__ wdw,
                       const float* __restrict__ bdw,
                       f16* __restrict__ xt, f16* __restrict__ rbt) {
    int ht = blockIdx.x, ct = blockIdx.y, b = blockIdx.z;
    __shared__ float xs[64 * 129];
    int t = threadIdx.x;
    int h0 = ht * 2;
#pragma unroll
    for (int i = 0; i < 8; ++i) {
        int idx = t + i * 256;
        int cl = idx >> 5, col4 = idx & 31;
        int hh = h0 - 1 + (col4 >> 3);
        int wq = (col4 & 7) * 4;
        float4 v = make_float4(0.f, 0.f, 0.f, 0.f);
        if (hh >= 0 && hh < 32)
            v = *(const float4*)(x + (size_t)(b * 384 + ct * 64 + cl) * 1024 + hh * 32 + wq);
        int base = cl * 129 + col4 * 4;
        xs[base] = v.x; xs[base + 1] = v.y; xs[base + 2] = v.z; xs[base + 3] = v.w;
    }
    __syncthreads();
    int cl = t & 63;
    int c = ct * 64 + cl;
    float wd[9];
#pragma unroll
    for (int k = 0; k < 9; ++k) wd[k] = wdw[c * 9 + k];
    float bd = bdw[c];
    const float* row = &xs[cl * 129];
    int nb = (t >> 6) * 16;
#pragma unroll
    for (int i = 0; i < 16; ++i) {
        int nl = nb + i;
        int hh = nl >> 5, ww = nl & 31;
        int lx = hh + 1;
        float acc = bd;
#pragma unroll
        for (int dh = -1; dh <= 1; ++dh) {
#pragma unroll
            for (int dw = -1; dw <= 1; ++dw) {
                int w2 = ww + dw;
                if (w2 >= 0 && w2 <= 31)
                    acc += wd[(dh + 1) * 3 + (dw + 1)] * row[(lx + dh) * 32 + w2];
            }
        }
        float xc = row[lx * 32 + ww];
        size_t at = ((size_t)(b * 1024) + h0 * 32 + nl) * 384 + c;
        rbt[at] = (f16)acc;
        xt[at] = (f16)xc;
    }
}

// ---------------- QKV GEMM (global_load_lds staging, pre-swizzled source) ----------------
// grid: (bm=8, bn=9, b=16), 256 threads (4 waves, 2x2), tile 128x128, BK=64. 32 KB static LDS.
__launch_bounds__(256, 2)
__global__ void k_gemm1(const f16* __restrict__ xt, const f16* __restrict__ wh,
                        const float* __restrict__ bias, const f16* __restrict__ rbt,
                        f16* __restrict__ qo, f16* __restrict__ krb, f16* __restrict__ vt) {
    __shared__ f16 As[128 * 64];
    __shared__ f16 Bs[128 * 64];
    int bm = blockIdx.x, bn = blockIdx.y, b = blockIdx.z;
    int t = threadIdx.x, lane = t & 63, wv = t >> 6;
    int wm = wv >> 1, wn = wv & 1;
    f32x4 acc[4][4] = {};
    const char* xbase = (const char*)(xt + (size_t)(b * 1024 + bm * 128) * 384);
    const char* wbase = (const char*)(wh + (size_t)(bn * 128) * 384);
    const bool vmode = (bn >= 6);
    int soff[4];
#pragma unroll
    for (int i = 0; i < 4; ++i) {
        int idx = i * 256 + t;            // granule in 128row x 8granule tile
        int r = idx >> 3, cg = idx & 7;
        soff[i] = r * 768 + ((cg ^ (r & 7)) << 4);
    }
    for (int kc = 0; kc < 6; ++kc) {
        __syncthreads();
#pragma unroll
        for (int i = 0; i < 4; ++i) {
            gl2lds(xbase + kc * 128 + soff[i], (char*)As + (i * 256 + wv * 64) * 16);
            gl2lds(wbase + kc * 128 + soff[i], (char*)Bs + (i * 256 + wv * 64) * 16);
        }
        __syncthreads();
#pragma unroll
        for (int j = 0; j < 2; ++j) {
            f16x8 af[4], bf[4];
#pragma unroll
            for (int mr = 0; mr < 4; ++mr) {
                int rowi = wm * 64 + mr * 16 + (lane & 15);
                af[mr] = *(const f16x8*)((const char*)As + rowi * 128 +
                         ((j * 64 + (lane >> 4) * 16) ^ ((rowi & 7) << 4)));
            }
#pragma unroll
            for (int nr = 0; nr < 4; ++nr) {
                int rowi = wn * 64 + nr * 16 + (lane & 15);
                bf[nr] = *(const f16x8*)((const char*)Bs + rowi * 128 +
                         ((j * 64 + (lane >> 4) * 16) ^ ((rowi & 7) << 4)));
            }
            __builtin_amdgcn_s_setprio(1);
            if (!vmode) {
#pragma unroll
                for (int mr = 0; mr < 4; ++mr)
#pragma unroll
                    for (int nr = 0; nr < 4; ++nr)
                        acc[mr][nr] = __builtin_amdgcn_mfma_f32_16x16x32_f16(af[mr], bf[nr], acc[mr][nr], 0, 0, 0);
            } else {
#pragma unroll
                for (int mr = 0; mr < 4; ++mr)
#pragma unroll
                    for (int nr = 0; nr < 4; ++nr)
                        acc[mr][nr] = __builtin_amdgcn_mfma_f32_16x16x32_f16(bf[nr], af[mr], acc[mr][nr], 0, 0, 0);
            }
            __builtin_amdgcn_s_setprio(0);
        }
    }
    int o0 = bn * 128;
    if (!vmode) {
#pragma unroll
        for (int nr = 0; nr < 4; ++nr) {
            int o = o0 + wn * 64 + nr * 16 + (lane & 15);
            float bs = bias[o];
#pragma unroll
            for (int mr = 0; mr < 4; ++mr) {
                int n_l = wm * 64 + mr * 16 + ((lane >> 4) << 2);
#pragma unroll
                for (int r = 0; r < 4; ++r) {
                    int n_sp = bm * 128 + n_l + r;
                    size_t at = (size_t)(b * 1024 + n_sp) * 384;
                    float vv = acc[mr][nr][r] + bs;
                    if (o < 384) qo[at + o] = (f16)vv;
                    else krb[at + (o - 384)] = (f16)(vv + (float)rbt[at + (o - 384)]);
                }
            }
        }
    } else {
#pragma unroll
        for (int nr = 0; nr < 4; ++nr) {
#pragma unroll
            for (int mr = 0; mr < 4; ++mr) {
                int n_sp = bm * 128 + wm * 64 + mr * 16 + (lane & 15);
                int o_l = wn * 64 + nr * 16 + ((lane >> 4) << 2);
#pragma unroll
                for (int r = 0; r < 4; ++r) {
                    float vv = acc[mr][nr][r] + bias[o0 + o_l + r];
                    vt[(size_t)(b * 384 + (o0 - 768) + o_l + r) * 1024 + n_sp] = (f16)vv;
                }
            }
        }
    }
}

// ---------------- flash attention v3: KVBLK=32, 48 KB STATIC LDS ----------------
// grid: (qt=16, b=16), 256 threads (4 waves, wave owns 16 q-rows).
// Ks [32 kv][384 c] f16 (24 KB, row 768 B) + Vs [384 c][32 kv] f16 (24 KB, row 64 B).
__launch_bounds__(256, 1)
__global__ void k_flash3(const f16* __restrict__ q, const f16* __restrict__ krb,
                         const f16* __restrict__ vt, float* __restrict__ out) {
    __shared__ char smem[49152];
    char* Ks = smem;
    char* Vs = smem + 24576;
    int qt = blockIdx.x, b = blockIdx.y;
    int t = threadIdx.x, lane = t & 63, wv = t >> 6;
    int g = lane >> 4, ln = lane & 15;
    int n0 = qt * 64;

    // Q as B-fragment: col=q (ln), k = g*8+e within each 32-channel chunk
    f16x8 qf[12];
    {
        const f16* qb = q + (size_t)(b * 1024 + n0 + wv * 16 + ln) * 384 + g * 8;
#pragma unroll
        for (int kc = 0; kc < 12; ++kc) qf[kc] = *(const f16x8*)(qb + kc * 32);
    }

    // staging source offsets (pre-swizzled global source; linear LDS dest)
    int koff[6], voff[6];
#pragma unroll
    for (int i = 0; i < 6; ++i) {
        int idx = i * 256 + t;                         // 1536 granules
        int r = idx / 48, c = idx - r * 48;            // K: 32 rows x 48 granules
        koff[i] = r * 768 + ((c ^ (r & 7)) << 4);
        int vr = idx >> 2, vc = idx & 3;               // V: 384 rows x 4 granules
        voff[i] = vr * 2048 + ((vc ^ (vr & 3)) << 4);  // global row stride 2048 B
    }
    const char* kbase = (const char*)(krb + (size_t)b * 1024 * 384);
    const char* vbase = (const char*)(vt + (size_t)b * 384 * 1024);

    // prologue: stage K[0]
#pragma unroll
    for (int i = 0; i < 6; ++i)
        gl2lds(kbase + koff[i], Ks + (i * 256 + wv * 64) * 16);

    f32x4 oa[24];
#pragma unroll
    for (int i = 0; i < 24; ++i) oa[i] = (f32x4){0.f, 0.f, 0.f, 0.f};
    float m_run = -1e30f, l_run = 0.f;
    int src0 = 2 * (g & 1) * 16 + ln, src1 = src0 + 16;
    bool gh = (g >= 2);

    for (int kt = 0; kt < 32; ++kt) {
        __syncthreads();               // K[kt] ready; Vs free (prev PV done)
        // async stage V[kt] (flies under QK)
#pragma unroll
        for (int i = 0; i < 6; ++i)
            gl2lds(vbase + kt * 64 + voff[i], Vs + (i * 256 + wv * 64) * 16);

        // QK^T swapped: S^T[kv][q], kv = nr*16 + g*4 + r, q = ln
        f32x4 st[2] = {};
        __builtin_amdgcn_s_setprio(1);
#pragma unroll
        for (int kc = 0; kc < 12; ++kc) {
#pragma unroll
            for (int nr = 0; nr < 2; ++nr) {
                int kvr = nr * 16 + ln;
                f16x8 kf = *(const f16x8*)(Ks + kvr * 768 +
                            ((kc * 64 + g * 16) ^ ((kvr & 7) << 4)));
                st[nr] = __builtin_amdgcn_mfma_f32_16x16x32_f16(kf, qf[kc], st[nr], 0, 0, 0);
            }
        }
        __builtin_amdgcn_s_setprio(0);

        // register online softmax (per-lane q = ln; kv spread over g/regs)
        float mx = st[0][0];
#pragma unroll
        for (int nr = 0; nr < 2; ++nr)
#pragma unroll
            for (int r = 0; r < 4; ++r) mx = fmaxf(mx, st[nr][r]);
        mx = fmaxf(mx, __shfl_xor(mx, 16));
        mx = fmaxf(mx, __shfl_xor(mx, 32));
        float mn = fmaxf(m_run, mx);
        float sc = exp2f((m_run - mn) * L2E);
        m_run = mn;
        float ls = 0.f;
        float pv[2][4];
#pragma unroll
        for (int nr = 0; nr < 2; ++nr)
#pragma unroll
            for (int r = 0; r < 4; ++r) {
                float p = exp2f((st[nr][r] - mn) * L2E);
                pv[nr][r] = p;
                ls += p;
            }
        ls += __shfl_xor(ls, 16);
        ls += __shfl_xor(ls, 32);
        l_run = l_run * sc + ls;
#pragma unroll
        for (int i = 0; i < 24; ++i) oa[i] *= sc;

        // pack P^T to f16 pairs, shuffle into PV B-fragment (k=kv, col=q)
        int pk[4];
#pragma unroll
        for (int nr = 0; nr < 2; ++nr)
#pragma unroll
            for (int h = 0; h < 2; ++h) {
                f16x2 w2 = { (f16)pv[nr][2 * h], (f16)pv[nr][2 * h + 1] };
                pk[nr * 2 + h] = __builtin_bit_cast(int, w2);
            }
        f16x8 pb;
        {
            int a0 = __shfl(pk[0], src0);
            int a1 = __shfl(pk[1], src0);
            int a2 = __shfl(pk[2], src0);
            int a3 = __shfl(pk[3], src0);
            int b0 = __shfl(pk[0], src1);
            int b1 = __shfl(pk[1], src1);
            int b2 = __shfl(pk[2], src1);
            int b3 = __shfl(pk[3], src1);
            union { int w[4]; f16x8 v; } u;
            u.w[0] = gh ? a2 : a0;
            u.w[1] = gh ? a3 : a1;
            u.w[2] = gh ? b2 : b0;
            u.w[3] = gh ? b3 : b1;
            pb = u.v;
        }

        __syncthreads();               // V[kt] ready; Ks consumed
        if (kt < 31) {                 // async stage K[kt+1] (flies under PV)
#pragma unroll
            for (int i = 0; i < 6; ++i)
                gl2lds(kbase + (kt + 1) * 24576 + koff[i], Ks + (i * 256 + wv * 64) * 16);
        }

        // PV: O^T[c][q] += V^T-tile x P^T  (K = 32, one MFMA per c-block)
        __builtin_amdgcn_s_setprio(1);
#pragma unroll
        for (int nr2 = 0; nr2 < 24; ++nr2) {
            int cr = nr2 * 16 + ln;
            f16x8 vf = *(const f16x8*)(Vs + cr * 64 +
                        ((g * 16) ^ ((cr & 3) << 4)));
            oa[nr2] = __builtin_amdgcn_mfma_f32_16x16x32_f16(vf, pb, oa[nr2], 0, 0, 0);
        }
        __builtin_amdgcn_s_setprio(0);
    }

    // epilogue: O^T/l -> out[b][c][n]
    float inv = 1.0f / l_run;
#pragma unroll
    for (int nr2 = 0; nr2 < 24; ++nr2) {
#pragma unroll
        for (int r = 0; r < 4; ++r) {
            int c = nr2 * 16 + g * 4 + r;
            out[(size_t)(b * 384 + c) * 1024 + n0 + wv * 16 + ln] = oa[nr2][r] * inv;
        }
    }
}

extern "C" void kernel_launch(void* const* d_in, const int* in_sizes, int n_in,
                              void* d_out, int out_size, void* d_ws, size_t ws_size,
                              hipStream_t stream) {
    const float* x     = (const float*)d_in[0];
    const float* w_qkv = (const float*)d_in[1];
    const float* b_qkv = (const float*)d_in[2];
    const float* w_dw  = (const float*)d_in[3];
    const float* b_dw  = (const float*)d_in[4];
    float* out = (float*)d_out;
    char* ws = (char*)d_ws;
    const size_t SZ = (size_t)16 * 1024 * 384 * 2;
    f16* xt  = (f16*)(ws);
    f16* rbt = (f16*)(ws + SZ);
    f16* qo  = (f16*)(ws + 2 * SZ);
    f16* krb = (f16*)(ws + 3 * SZ);
    f16* vt  = (f16*)(ws + 4 * SZ);
    f16* wh  = (f16*)(ws + 5 * SZ);

    k_wcvt<<<432, 256, 0, stream>>>(w_qkv, wh);
    k_prep<<<dim3(16, 6, 16), 256, 0, stream>>>(x, w_dw, b_dw, xt, rbt);
    k_gemm1<<<dim3(8, 9, 16), 256, 0, stream>>>(xt, wh, b_qkv, rbt, qo, krb, vt);
    k_flash3<<<dim3(16, 16), 256, 0, stream>>>(qo, krb, vt, out);
}